// Round 6
// baseline (264.557 us; speedup 1.0000x reference)
//
#include <hip/hip_runtime.h>
#include <hip/hip_bf16.h>

// CausalMixer: B=128, T=64, NA=10, NV=16, K=4, SD=512, H=256, E=32. 8192 rows.
// Round 6: SINGLE kernel. 32 rows/block, 256 blocks, 512 threads (8 waves).
// B-operands JIT-packed per wave: coalesced float4 reads of native weights ->
// per-wave LDS transpose buffer (no barriers) -> b128 MFMA fragments.
// A-fragments held in registers across all N-strips. No workspace, no prep.

typedef __hip_bfloat16 bf16;
typedef unsigned short ushort_t;
typedef __attribute__((ext_vector_type(8))) short short8;
typedef __attribute__((ext_vector_type(4))) float f32x4;
typedef __attribute__((ext_vector_type(4))) unsigned int u32x4;
typedef __attribute__((ext_vector_type(4))) unsigned short u16x4;

#define MFMA16(a, b, c) __builtin_amdgcn_mfma_f32_16x16x32_bf16(a, b, c, 0, 0, 0)

__device__ __forceinline__ float us2f(ushort_t x) {
  unsigned u = ((unsigned)x) << 16; float f; __builtin_memcpy(&f, &u, 4); return f;
}
__device__ __forceinline__ ushort_t f2us(float v) {
  bf16 h = __float2bfloat16(v); ushort_t r; __builtin_memcpy(&r, &h, 2); return r;
}
template <bool F32>
__device__ __forceinline__ float LD(const void* p, size_t i) {
  if (F32) return ((const float*)p)[i];
  return us2f(((const ushort_t*)p)[i]);
}
// load 4 consecutive cols at (row,col) and convert to bf16
template <bool F32>
__device__ __forceinline__ void ldcvt4(const void* src, size_t idx, ushort_t v[4]) {
  if (F32) {
    f32x4 x = *(const f32x4*)((const float*)src + idx);
    v[0] = f2us(x[0]); v[1] = f2us(x[1]); v[2] = f2us(x[2]); v[3] = f2us(x[3]);
  } else {
    u16x4 x = *(const u16x4*)((const ushort_t*)src + idx);
    v[0] = x[0]; v[1] = x[1]; v[2] = x[2]; v[3] = x[3];
  }
}

// wave-level dtype probe: 1 = float32, 0 = bf16
__device__ __forceinline__ int detect_f32(const void* states) {
  const unsigned short* u = (const unsigned short*)states;
  int lane = threadIdx.x & 63;
  int bad = 0;
  for (int i = lane; i < 512; i += 64) {
    unsigned short x = u[i];
    int e = (x >> 7) & 0xFF;
    if (e > 140 || (((x & 0x7FFFu) != 0) && e < 100)) bad++;
  }
  for (int off = 32; off; off >>= 1) bad += __shfl_down(bad, off);
  return __shfl(bad, 0) > 20;
}

struct SmemM {
  union {
    __align__(16) ushort_t sA[2][8192];   // states, MFMA lane order (phase A)
    __align__(16) ushort_t w1a[32][548];  // |w1 raw| bf16 (phase B output)
  } u;
  __align__(16) unsigned int cb[8 * 2 * 320];  // per-wave dbuf transpose chunks
  __align__(16) ushort_t Am1[2][4096];    // relu(s@w1l1+b), lane order
  __align__(16) ushort_t Am2[2][4096];    // relu(s@w2l1+b), lane order
  __align__(16) ushort_t hb[32][264];     // s@w00l1+b (pre-relu), linear
  float hd[256]; float gd;
  float b1v[32][32];
  float rbv[32][32];
  float w2v[32][32];
  float w01v[32][12];
  float qv[32][10];
  unsigned char cr[32][64];
  float w0c[32][4], w0s[32][4];
  float gq[32][18];
  float gbv[32], b01v[32];
  float hid[32][33];
};

template <bool F32>
__device__ void mixer_body(SmemM& sm, int n0,
    const void* qvals, const int* crel, const void* states,
    const void* w00l1W, const void* w00l1b, const void* w00l2W, const void* w00l2b,
    const void* b00W, const void* b00b,
    const void* w01W, const void* w01b, const void* b01W, const void* b01b,
    const void* w1l1W, const void* w1l1b, const void* w1l2W, const void* w1l2b,
    const void* b1W, const void* b1b,
    const void* w2l1W, const void* w2l1b, const void* w2l2W, const void* w2l2b,
    const void* b2l1W, const void* b2l1b, const void* b2l2W, const void* b2l2b,
    void* out) {
  const int tid = threadIdx.x;                // 0..511
  const int lane = tid & 63, wv = tid >> 6;   // 8 waves
  const int q = lane >> 4, lm = lane & 15;
  const int pr = lane & 15, ng = lane >> 4;   // staging roles
  const int b_blk = n0 >> 6;

  // ---- stage: states -> sA in MFMA lane order; qv/cr; hd/gd ----
  for (int fi = tid; fi < 2048; fi += 512) {
    int ln = fi & 63, ks = (fi >> 6) & 15, G = fi >> 10;
    int row = G * 16 + (ln & 15), col = ks * 32 + (ln >> 4) * 8;
    if (F32) {
      const f32x4* p = (const f32x4*)((const float*)states + (size_t)(n0 + row) * 512 + col);
      f32x4 v0 = p[0], v1 = p[1];
      ushort_t v[8];
      v[0] = f2us(v0[0]); v[1] = f2us(v0[1]); v[2] = f2us(v0[2]); v[3] = f2us(v0[3]);
      v[4] = f2us(v1[0]); v[5] = f2us(v1[1]); v[6] = f2us(v1[2]); v[7] = f2us(v1[3]);
      *(short8*)&sm.u.sA[G][(size_t)(ks * 64 + ln) * 8] = *(short8*)v;
    } else {
      *(short8*)&sm.u.sA[G][(size_t)(ks * 64 + ln) * 8] =
          *(const short8*)((const ushort_t*)states + (size_t)(n0 + row) * 512 + col);
    }
  }
  for (int i = tid; i < 320; i += 512) sm.qv[i / 10][i % 10] = LD<F32>(qvals, (size_t)(n0 + i / 10) * 10 + i % 10);
  for (int i = tid; i < 2048; i += 512) sm.cr[i >> 6][i & 63] = (unsigned char)crel[(size_t)n0 * 64 + i];
  if (tid < 256) {
    float s = 0.f;
    for (int z = 0; z < 16; ++z) s += LD<F32>(w00l1W, (size_t)(512 + z) * 256 + tid);
    sm.hd[tid] = s;
  } else if (tid == 256) {
    float s = 0.f;
    for (int z = 0; z < 16; ++z) s += LD<F32>(b00W, 512 + z);
    sm.gd = s;
  }
  __syncthreads();

  // ---- A-fragments into registers (128 VGPR) ----
  short8 afr0[16], afr1[16];
#pragma unroll
  for (int ks = 0; ks < 16; ++ks) {
    afr0[ks] = *(const short8*)&sm.u.sA[0][(ks * 64 + lane) * 8];
    afr1[ks] = *(const short8*)&sm.u.sA[1][(ks * 64 + lane) * 8];
  }
  unsigned int* cb0 = sm.cb + wv * 640;

  // ---- Phase A: Y(32x844) = S @ Wcat^T, 53 strips of 16 cols, K=512 ----
  for (int s = wv; s < 53; s += 8) {
    const void* src = nullptr; int stride = 0, nn0 = 0; bool mixed = false;
    if (s < 16)      { src = w1l1W;  stride = 256; nn0 = s * 16; }
    else if (s < 32) { src = w2l1W;  stride = 256; nn0 = s * 16 - 256; }
    else if (s < 48) { src = w00l1W; stride = 256; nn0 = s * 16 - 512; }
    else if (s < 50) { src = b1W;    stride = 32;  nn0 = s * 16 - 768; }
    else if (s < 52) { src = b2l1W;  stride = 32;  nn0 = s * 16 - 800; }
    else mixed = true;
    f32x4 acc0 = {0.f, 0.f, 0.f, 0.f}, acc1 = {0.f, 0.f, 0.f, 0.f};
#pragma unroll
    for (int ks = 0; ks < 16; ++ks) {
      unsigned int* buf = cb0 + (ks & 1) * 320;
      ushort_t v0[4], v1[4];
      int k0 = ks * 32 + pr * 2;
      if (!mixed) {
        ldcvt4<F32>(src, (size_t)k0 * stride + nn0 + ng * 4, v0);
        ldcvt4<F32>(src, (size_t)(k0 + 1) * stride + nn0 + ng * 4, v1);
      } else {
#pragma unroll
        for (int i = 0; i < 4; ++i) {
          int n = 832 + ng * 4 + i;
          float x0, x1;
          if (n < 842)      { x0 = LD<F32>(w01W, (size_t)k0 * 10 + n - 832); x1 = LD<F32>(w01W, (size_t)(k0 + 1) * 10 + n - 832); }
          else if (n == 842){ x0 = LD<F32>(b00W, k0); x1 = LD<F32>(b00W, k0 + 1); }
          else if (n == 843){ x0 = LD<F32>(b01W, k0); x1 = LD<F32>(b01W, k0 + 1); }
          else              { x0 = 0.f; x1 = 0.f; }
          v0[i] = f2us(x0); v1[i] = f2us(x1);
        }
      }
#pragma unroll
      for (int i = 0; i < 4; ++i)
        buf[(ng * 4 + i) * 20 + pr] = (unsigned)v0[i] | ((unsigned)v1[i] << 16);
      u32x4 t = *(const u32x4*)&buf[lm * 20 + q * 4];
      short8 bfrag; __builtin_memcpy(&bfrag, &t, 16);
      acc0 = MFMA16(afr0[ks], bfrag, acc0);
      acc1 = MFMA16(afr1[ks], bfrag, acc1);
    }
    int c = s * 16 + lm;
    if (c < 844) {
      float bias;
      if (c < 256)       bias = LD<F32>(w1l1b, c);
      else if (c < 512)  bias = LD<F32>(w2l1b, c - 256);
      else if (c < 768)  bias = LD<F32>(w00l1b, c - 512);
      else if (c < 800)  bias = LD<F32>(b1b, c - 768);
      else if (c < 832)  bias = LD<F32>(b2l1b, c - 800);
      else if (c < 842)  bias = LD<F32>(w01b, c - 832);
      else if (c == 842) bias = LD<F32>(b00b, 0);
      else               bias = LD<F32>(b01b, 0);
      int ks2 = (c & 255) >> 5, q2 = (c >> 3) & 3, j2 = c & 7;
#pragma unroll
      for (int G = 0; G < 2; ++G) {
        f32x4 acc = G ? acc1 : acc0;
        int rb = G * 16 + q * 4;
        if (c < 256) {
#pragma unroll
          for (int g = 0; g < 4; ++g) {
            float v = acc[g] + bias;
            sm.Am1[G][(ks2 * 64 + q2 * 16 + q * 4 + g) * 8 + j2] = f2us(v > 0.f ? v : 0.f);
          }
        } else if (c < 512) {
#pragma unroll
          for (int g = 0; g < 4; ++g) {
            float v = acc[g] + bias;
            sm.Am2[G][(ks2 * 64 + q2 * 16 + q * 4 + g) * 8 + j2] = f2us(v > 0.f ? v : 0.f);
          }
        } else if (c < 768) {
#pragma unroll
          for (int g = 0; g < 4; ++g) sm.hb[rb + g][c - 512] = f2us(acc[g] + bias);
        } else if (c < 800) {
#pragma unroll
          for (int g = 0; g < 4; ++g) sm.b1v[rb + g][c - 768] = acc[g] + bias;
        } else if (c < 832) {
#pragma unroll
          for (int g = 0; g < 4; ++g) { float v = acc[g] + bias; sm.rbv[rb + g][c - 800] = v > 0.f ? v : 0.f; }
        } else if (c < 842) {
#pragma unroll
          for (int g = 0; g < 4; ++g) sm.w01v[rb + g][c - 832] = acc[g] + bias;
        } else if (c == 842) {
#pragma unroll
          for (int g = 0; g < 4; ++g) sm.gbv[rb + g] = acc[g] + bias;
        } else {
#pragma unroll
          for (int g = 0; g < 4; ++g) sm.b01v[rb + g] = acc[g] + bias;
        }
      }
    }
  }
  __syncthreads();

  // ---- Phase B: strips 0..33 = m1 @ w1l2; 34..35 = m2 @ w2l2, K=256 ----
  short8 bf0[8], bf1[8];
#pragma unroll
  for (int ks = 0; ks < 8; ++ks) {
    bf0[ks] = *(const short8*)&sm.Am1[0][(ks * 64 + lane) * 8];
    bf1[ks] = *(const short8*)&sm.Am1[1][(ks * 64 + lane) * 8];
  }
  bool have_m2 = false;
  for (int s = wv; s < 36; s += 8) {
    if (s >= 34 && !have_m2) {
#pragma unroll
      for (int ks = 0; ks < 8; ++ks) {
        bf0[ks] = *(const short8*)&sm.Am2[0][(ks * 64 + lane) * 8];
        bf1[ks] = *(const short8*)&sm.Am2[1][(ks * 64 + lane) * 8];
      }
      have_m2 = true;
    }
    const void* src; int stride, nn0;
    if (s < 34) { src = w1l2W; stride = 544; nn0 = s * 16; }
    else        { src = w2l2W; stride = 32;  nn0 = s * 16 - 544; }
    f32x4 acc0 = {0.f, 0.f, 0.f, 0.f}, acc1 = {0.f, 0.f, 0.f, 0.f};
#pragma unroll
    for (int ks = 0; ks < 8; ++ks) {
      unsigned int* buf = cb0 + (ks & 1) * 320;
      ushort_t v0[4], v1[4];
      int k0 = ks * 32 + pr * 2;
      ldcvt4<F32>(src, (size_t)k0 * stride + nn0 + ng * 4, v0);
      ldcvt4<F32>(src, (size_t)(k0 + 1) * stride + nn0 + ng * 4, v1);
#pragma unroll
      for (int i = 0; i < 4; ++i)
        buf[(ng * 4 + i) * 20 + pr] = (unsigned)v0[i] | ((unsigned)v1[i] << 16);
      u32x4 t = *(const u32x4*)&buf[lm * 20 + q * 4];
      short8 bfrag; __builtin_memcpy(&bfrag, &t, 16);
      acc0 = MFMA16(bf0[ks], bfrag, acc0);
      acc1 = MFMA16(bf1[ks], bfrag, acc1);
    }
    int c = s * 16 + lm;
    float bias = (c < 544) ? LD<F32>(w1l2b, c) : LD<F32>(w2l2b, c - 544);
#pragma unroll
    for (int G = 0; G < 2; ++G) {
      f32x4 acc = G ? acc1 : acc0;
      int rb = G * 16 + q * 4;
      if (c < 544) {
#pragma unroll
        for (int g = 0; g < 4; ++g) sm.u.w1a[rb + g][c] = f2us(fabsf(acc[g] + bias));
      } else {
        int e = c - 544;
#pragma unroll
        for (int g = 0; g < 4; ++g) sm.w2v[rb + g][e] = fabsf(acc[g] + bias);
      }
    }
  }
  __syncthreads();

  // ---- C1: w0c/w0s = relu(hb [+hd]) @ w00l2 + b ----
  if (tid < 256) {
    int r = tid >> 3, k = (tid >> 1) & 3, sflag = tid & 1;
    float a = 0.f;
    for (int j = 0; j < 256; ++j) {
      float h = us2f(sm.hb[r][j]);
      if (sflag) h += sm.hd[j];
      h = h > 0.f ? h : 0.f;
      a = fmaf(h, LD<F32>(w00l2W, j * 4 + k), a);
    }
    a += LD<F32>(w00l2b, k);
    if (sflag) sm.w0s[r][k] = a; else sm.w0c[r][k] = a;
  }
  __syncthreads();

  // ---- C2: gq ----
  {
    int r = tid >> 4, v = tid & 15;
    bool sp = (v == b_blk);
    const float* w0 = sp ? sm.w0s[r] : sm.w0c[r];
    float g = sm.gbv[r] + (sp ? sm.gd : 0.f);
#pragma unroll
    for (int k = 0; k < 4; ++k) {
      int a = sm.cr[r][k * 16 + v];
      g = fmaf(sm.qv[r][a], fabsf(w0[k]), g);
    }
    sm.gq[r][v] = g;
  }
  if (tid < 32) {
    float o = sm.b01v[tid];
#pragma unroll
    for (int a = 0; a < 10; ++a) o = fmaf(sm.qv[tid][a], sm.w01v[tid][a], o);
    sm.gq[tid][16] = o;
  }
  __syncthreads();

  // ---- C3: hidden = elu(sum_v gq*|w1| + b1); fuse *w2 + rb*b2l2W ----
  for (int p = tid; p < 1024; p += 512) {
    int r = p >> 5, e = p & 31;
    float h = sm.b1v[r][e];
#pragma unroll
    for (int v = 0; v < 17; ++v) h = fmaf(sm.gq[r][v], us2f(sm.u.w1a[r][v * 32 + e]), h);
    float hid = h > 0.f ? h : (expf(h) - 1.f);
    sm.hid[r][e] = hid * sm.w2v[r][e] + sm.rbv[r][e] * LD<F32>(b2l2W, e);
  }
  __syncthreads();

  // ---- C4: reduce + store ----
  if (tid < 32) {
    float y = LD<F32>(b2l2b, 0);
#pragma unroll
    for (int e = 0; e < 32; ++e) y += sm.hid[tid][e];
    if (F32) ((float*)out)[n0 + tid] = y;
    else ((bf16*)out)[n0 + tid] = __float2bfloat16(y);
  }
}

__global__ __launch_bounds__(512, 2) void causal_mixer_fused(
    const void* qvals, const int* crel, const void* states,
    const void* w00l1W, const void* w00l1b, const void* w00l2W, const void* w00l2b,
    const void* b00W, const void* b00b,
    const void* w01W, const void* w01b, const void* b01W, const void* b01b,
    const void* w1l1W, const void* w1l1b, const void* w1l2W, const void* w1l2b,
    const void* b1W, const void* b1b,
    const void* w2l1W, const void* w2l1b, const void* w2l2W, const void* w2l2b,
    const void* b2l1W, const void* b2l1b, const void* b2l2W, const void* b2l2b,
    void* out) {
  __shared__ SmemM sm;
  int n0 = blockIdx.x * 32;
  if (detect_f32(states))
    mixer_body<true>(sm, n0, qvals, crel, states,
        w00l1W, w00l1b, w00l2W, w00l2b, b00W, b00b, w01W, w01b, b01W, b01b,
        w1l1W, w1l1b, w1l2W, w1l2b, b1W, b1b, w2l1W, w2l1b, w2l2W, w2l2b,
        b2l1W, b2l1b, b2l2W, b2l2b, out);
  else
    mixer_body<false>(sm, n0, qvals, crel, states,
        w00l1W, w00l1b, w00l2W, w00l2b, b00W, b00b, w01W, w01b, b01W, b01b,
        w1l1W, w1l1b, w1l2W, w1l2b, b1W, b1b, w2l1W, w2l1b, w2l2W, w2l2b,
        b2l1W, b2l1b, b2l2W, b2l2b, out);
}

extern "C" void kernel_launch(void* const* d_in, const int* in_sizes, int n_in,
                              void* d_out, int out_size, void* d_ws, size_t ws_size,
                              hipStream_t stream) {
  (void)d_ws; (void)ws_size;
  hipLaunchKernelGGL(causal_mixer_fused, dim3(256), dim3(512), 0, stream,
      d_in[0], (const int*)d_in[1], d_in[2],
      d_in[3], d_in[4], d_in[5], d_in[6], d_in[7], d_in[8],
      d_in[9], d_in[10], d_in[11], d_in[12],
      d_in[13], d_in[14], d_in[15], d_in[16], d_in[17], d_in[18],
      d_in[19], d_in[20], d_in[21], d_in[22], d_in[23], d_in[24],
      d_in[25], d_in[26],
      d_out);
}

// Round 7
// 176.400 us; speedup vs baseline: 1.4998x; 1.4998x over previous
//
#include <hip/hip_runtime.h>
#include <hip/hip_bf16.h>

// CausalMixer: B=128, T=64, NA=10, NV=16, K=4, SD=512, H=256, E=32. 8192 rows.
// Round 7: prep (packs weights bf16 in MFMA lane order into d_ws) + main
// (M=32 rows/block, 256 blocks = 1/CU, 8 waves). G0 A-frags in registers,
// single-strip N distribution, biases read from L2-hot ws (no cst staging).

typedef __hip_bfloat16 bf16;
typedef unsigned short ushort_t;
typedef __attribute__((ext_vector_type(8))) short short8;
typedef __attribute__((ext_vector_type(4))) float f32x4;

#define PA_OFF 0
#define PA_TILES 56                                  // N=896 padded (844 real)
#define PB_OFF (PA_TILES * 16 * 64 * 8 * 2)          // 917504
#define PB_TILES 36                                  // N=576 exact
#define FB_OFF (PB_OFF + PB_TILES * 8 * 64 * 8 * 2)  // 1212416
#define NCST 2854
#define WS_NEED (size_t)(FB_OFF + NCST * 4 + 32)

#define MFMA16(a, b, c) __builtin_amdgcn_mfma_f32_16x16x32_bf16(a, b, c, 0, 0, 0)

__device__ __forceinline__ float us2f(ushort_t x) {
  unsigned u = ((unsigned)x) << 16; float f; __builtin_memcpy(&f, &u, 4); return f;
}
__device__ __forceinline__ ushort_t f2us(float v) {
  bf16 h = __float2bfloat16(v); ushort_t r; __builtin_memcpy(&r, &h, 2); return r;
}
template <bool F32>
__device__ __forceinline__ float LD(const void* p, size_t i) {
  if (F32) return ((const float*)p)[i];
  return us2f(((const ushort_t*)p)[i]);
}

// wave-level dtype probe: 1 = float32, 0 = bf16
__device__ __forceinline__ int detect_f32(const void* states) {
  const unsigned short* u = (const unsigned short*)states;
  int lane = threadIdx.x & 63;
  int bad = 0;
  for (int i = lane; i < 512; i += 64) {
    unsigned short x = u[i];
    int e = (x >> 7) & 0xFF;
    if (e > 140 || (((x & 0x7FFFu) != 0) && e < 100)) bad++;
  }
  for (int off = 32; off; off >>= 1) bad += __shfl_down(bad, off);
  return __shfl(bad, 0) > 20;
}

// ---------------- prep: pack lane-ordered bf16 weights + f32 consts ----------------
template <bool F32>
__device__ void prep_body(int gtid, int T, char* ws,
    const void* w00l1W, const void* w00l1b, const void* w00l2W, const void* w00l2b,
    const void* b00W, const void* b00b,
    const void* w01W, const void* w01b, const void* b01W, const void* b01b,
    const void* w1l1W, const void* w1l1b, const void* w1l2W, const void* w1l2b,
    const void* b1W, const void* b1b,
    const void* w2l1W, const void* w2l1b, const void* w2l2W, const void* w2l2b,
    const void* b2l1W, const void* b2l1b, const void* b2l2W, const void* b2l2b) {
  ushort_t* pa = (ushort_t*)(ws + PA_OFF);
  ushort_t* pb = (ushort_t*)(ws + PB_OFF);
  float* cst = (float*)(ws + FB_OFF);
  for (int o = gtid; o < PA_TILES * 16 * 64; o += T) {
    int lane = o & 63, ks = (o >> 6) & 15, t = o >> 10;
    int lm = lane & 15, qq = lane >> 4;
    int n = t * 16 + lm, kb = ks * 32 + qq * 8;
    const void* src; int stride, nn;
    if (n < 256)       { src = w1l1W;  stride = 256; nn = n; }
    else if (n < 512)  { src = w2l1W;  stride = 256; nn = n - 256; }
    else if (n < 768)  { src = w00l1W; stride = 256; nn = n - 512; }
    else if (n < 800)  { src = b1W;    stride = 32;  nn = n - 768; }
    else if (n < 832)  { src = b2l1W;  stride = 32;  nn = n - 800; }
    else if (n < 842)  { src = w01W;   stride = 10;  nn = n - 832; }
    else if (n == 842) { src = b00W;   stride = 1;   nn = 0; }
    else if (n == 843) { src = b01W;   stride = 1;   nn = 0; }
    else               { src = nullptr; stride = 0;  nn = 0; }
    ushort_t v[8];
    if (src) {
#pragma unroll
      for (int j = 0; j < 8; ++j) v[j] = f2us(LD<F32>(src, (size_t)(kb + j) * stride + nn));
    } else {
#pragma unroll
      for (int j = 0; j < 8; ++j) v[j] = 0;
    }
    *(short8*)(pa + (size_t)o * 8) = *(short8*)v;
  }
  for (int o = gtid; o < PB_TILES * 8 * 64; o += T) {
    int lane = o & 63, ks = (o >> 6) & 7, t = o >> 9;
    int lm = lane & 15, qq = lane >> 4;
    int n = t * 16 + lm, kb = ks * 32 + qq * 8;
    const void* src; int stride, nn;
    if (n < 544) { src = w1l2W; stride = 544; nn = n; }
    else         { src = w2l2W; stride = 32;  nn = n - 544; }
    ushort_t v[8];
#pragma unroll
    for (int j = 0; j < 8; ++j) v[j] = f2us(LD<F32>(src, (size_t)(kb + j) * stride + nn));
    *(short8*)(pb + (size_t)o * 8) = *(short8*)v;
  }
  // consts: biasA[0,896) biasB[896,1536) hd[1536,1792) w00l2W[1792,2816)
  //         w00l2b[2816,2820) b2l2W[2820,2852) b2l2b[2852] gd[2853]
  for (int i = gtid; i < NCST; i += T) {
    float x;
    if (i < 896) {
      int c = i;
      if (c < 256) x = LD<F32>(w1l1b, c);
      else if (c < 512) x = LD<F32>(w2l1b, c - 256);
      else if (c < 768) x = LD<F32>(w00l1b, c - 512);
      else if (c < 800) x = LD<F32>(b1b, c - 768);
      else if (c < 832) x = LD<F32>(b2l1b, c - 800);
      else if (c < 842) x = LD<F32>(w01b, c - 832);
      else if (c == 842) x = LD<F32>(b00b, 0);
      else if (c == 843) x = LD<F32>(b01b, 0);
      else x = 0.f;
    } else if (i < 1536) {
      int c = i - 896;
      x = (c < 544) ? LD<F32>(w1l2b, c) : (c < 576 ? LD<F32>(w2l2b, c - 544) : 0.f);
    } else if (i < 1792) {
      int j = i - 1536; float s = 0.f;
      for (int z = 0; z < 16; ++z) s += LD<F32>(w00l1W, (size_t)(512 + z) * 256 + j);
      x = s;
    } else if (i < 2816) x = LD<F32>(w00l2W, i - 1792);
    else if (i < 2820) x = LD<F32>(w00l2b, i - 2816);
    else if (i < 2852) x = LD<F32>(b2l2W, i - 2820);
    else if (i == 2852) x = LD<F32>(b2l2b, 0);
    else { float s = 0.f; for (int z = 0; z < 16; ++z) s += LD<F32>(b00W, 512 + z); x = s; }
    cst[i] = x;
  }
}

__global__ __launch_bounds__(256) void prep_kernel(char* ws, const void* states,
    const void* w00l1W, const void* w00l1b, const void* w00l2W, const void* w00l2b,
    const void* b00W, const void* b00b,
    const void* w01W, const void* w01b, const void* b01W, const void* b01b,
    const void* w1l1W, const void* w1l1b, const void* w1l2W, const void* w1l2b,
    const void* b1W, const void* b1b,
    const void* w2l1W, const void* w2l1b, const void* w2l2W, const void* w2l2b,
    const void* b2l1W, const void* b2l1b, const void* b2l2W, const void* b2l2b) {
  int gtid = blockIdx.x * 256 + threadIdx.x;
  int T = gridDim.x * 256;
  if (detect_f32(states))
    prep_body<true>(gtid, T, ws, w00l1W, w00l1b, w00l2W, w00l2b, b00W, b00b,
        w01W, w01b, b01W, b01b, w1l1W, w1l1b, w1l2W, w1l2b, b1W, b1b,
        w2l1W, w2l1b, w2l2W, w2l2b, b2l1W, b2l1b, b2l2W, b2l2b);
  else
    prep_body<false>(gtid, T, ws, w00l1W, w00l1b, w00l2W, w00l2b, b00W, b00b,
        w01W, w01b, b01W, b01b, w1l1W, w1l1b, w1l2W, w1l2b, b1W, b1b,
        w2l1W, w2l1b, w2l2W, w2l2b, b2l1W, b2l1b, b2l2W, b2l2b);
}

// ---------------- main MFMA kernel: 32 rows/block, 8 waves ----------------
struct SmemM {
  union {
    __align__(16) ushort_t sA[2][8192];   // states, MFMA lane order (phase A only)
    __align__(16) ushort_t w1a[32][544];  // |w1 raw| bf16 (phase B output)
  } u;
  __align__(16) ushort_t Am1[2][4096];    // relu(s@w1l1+b), lane order
  __align__(16) ushort_t Am2[2][4096];    // relu(s@w2l1+b), lane order
  __align__(16) ushort_t hb[32][264];     // s@w00l1+b (pre-relu), linear
  float hd[256];
  float b1v[32][32];
  float rbv[32][32];
  float w2v[32][32];
  float w01v[32][12];
  float qv[32][10];
  unsigned char cr[32][64];
  float w0c[32][4], w0s[32][4];
  float gq[32][18];
  float gbv[32], b01v[32];
  float hid[32][33];
};

template <bool F32>
__device__ void mixer_body(SmemM& sm, const char* ws, int n0,
    const void* qvals, const int* crel, const void* states, void* out) {
  const int tid = threadIdx.x;                // 0..511
  const int lane = tid & 63, wv = tid >> 6;   // 8 waves
  const int q = lane >> 4, lm = lane & 15;
  const int b_blk = n0 >> 6;
  const ushort_t* pa = (const ushort_t*)(ws + PA_OFF);
  const ushort_t* pb = (const ushort_t*)(ws + PB_OFF);
  const float* cstg = (const float*)(ws + FB_OFF);

  // ---- stage: states -> sA in MFMA lane order; qv/cr; hd ----
  for (int fi = tid; fi < 2048; fi += 512) {
    int ln = fi & 63, ks = (fi >> 6) & 15, G = fi >> 10;
    int row = G * 16 + (ln & 15), col = ks * 32 + (ln >> 4) * 8;
    if (F32) {
      const f32x4* p = (const f32x4*)((const float*)states + (size_t)(n0 + row) * 512 + col);
      f32x4 v0 = p[0], v1 = p[1];
      ushort_t v[8];
      v[0] = f2us(v0[0]); v[1] = f2us(v0[1]); v[2] = f2us(v0[2]); v[3] = f2us(v0[3]);
      v[4] = f2us(v1[0]); v[5] = f2us(v1[1]); v[6] = f2us(v1[2]); v[7] = f2us(v1[3]);
      *(short8*)&sm.u.sA[G][(size_t)(ks * 64 + ln) * 8] = *(short8*)v;
    } else {
      *(short8*)&sm.u.sA[G][(size_t)(ks * 64 + ln) * 8] =
          *(const short8*)((const ushort_t*)states + (size_t)(n0 + row) * 512 + col);
    }
  }
  for (int i = tid; i < 320; i += 512) sm.qv[i / 10][i % 10] = LD<F32>(qvals, (size_t)(n0 + i / 10) * 10 + i % 10);
  for (int i = tid; i < 2048; i += 512) sm.cr[i >> 6][i & 63] = (unsigned char)crel[(size_t)n0 * 64 + i];
  if (tid < 256) sm.hd[tid] = cstg[1536 + tid];
  __syncthreads();

  // ---- G0 A-fragments into registers (64 VGPR); G1 stays in LDS ----
  short8 afr0[16];
#pragma unroll
  for (int ks = 0; ks < 16; ++ks)
    afr0[ks] = *(const short8*)&sm.u.sA[0][(ks * 64 + lane) * 8];

  // ---- Phase A: Y(32x844) = S @ WtA, 53 single strips, K=512 ----
  for (int s = wv; s < 53; s += 8) {
    const ushort_t* b0 = pa + (size_t)s * 8192 + lane * 8;
    f32x4 acc0 = {0.f, 0.f, 0.f, 0.f}, acc1 = {0.f, 0.f, 0.f, 0.f};
#pragma unroll
    for (int ks = 0; ks < 16; ++ks) {
      short8 bf = *(const short8*)(b0 + ks * 512);
      short8 a1 = *(const short8*)&sm.u.sA[1][(ks * 64 + lane) * 8];
      acc0 = MFMA16(afr0[ks], bf, acc0);
      acc1 = MFMA16(a1, bf, acc1);
    }
    int c = s * 16 + lm;
    if (c < 844) {
      float bias = cstg[c];
      int ks2 = (c & 255) >> 5, q2 = (c >> 3) & 3, j2 = c & 7;
#pragma unroll
      for (int G = 0; G < 2; ++G) {
        f32x4 acc = G ? acc1 : acc0;
        int rb = G * 16 + q * 4;
        if (c < 256) {
#pragma unroll
          for (int g = 0; g < 4; ++g) {
            float v = acc[g] + bias;
            sm.Am1[G][(ks2 * 64 + q2 * 16 + q * 4 + g) * 8 + j2] = f2us(v > 0.f ? v : 0.f);
          }
        } else if (c < 512) {
#pragma unroll
          for (int g = 0; g < 4; ++g) {
            float v = acc[g] + bias;
            sm.Am2[G][(ks2 * 64 + q2 * 16 + q * 4 + g) * 8 + j2] = f2us(v > 0.f ? v : 0.f);
          }
        } else if (c < 768) {
#pragma unroll
          for (int g = 0; g < 4; ++g) sm.hb[rb + g][c - 512] = f2us(acc[g] + bias);
        } else if (c < 800) {
#pragma unroll
          for (int g = 0; g < 4; ++g) sm.b1v[rb + g][c - 768] = acc[g] + bias;
        } else if (c < 832) {
#pragma unroll
          for (int g = 0; g < 4; ++g) { float v = acc[g] + bias; sm.rbv[rb + g][c - 800] = v > 0.f ? v : 0.f; }
        } else if (c < 842) {
#pragma unroll
          for (int g = 0; g < 4; ++g) sm.w01v[rb + g][c - 832] = acc[g] + bias;
        } else if (c == 842) {
#pragma unroll
          for (int g = 0; g < 4; ++g) sm.gbv[rb + g] = acc[g] + bias;
        } else {
#pragma unroll
          for (int g = 0; g < 4; ++g) sm.b01v[rb + g] = acc[g] + bias;
        }
      }
    }
  }
  __syncthreads();

  // ---- Phase B: strips 0..33 = m1 @ w1l2; 34..35 = m2 @ w2l2, K=256 ----
  // (w1a union overlays sA, which is dead after the barrier above)
  for (int t = wv; t < 36; t += 8) {
    const ushort_t* A0 = (t < 34) ? sm.Am1[0] : sm.Am2[0];
    const ushort_t* A1 = (t < 34) ? sm.Am1[1] : sm.Am2[1];
    const ushort_t* b0 = pb + (size_t)t * 4096 + lane * 8;
    f32x4 c0 = {0.f, 0.f, 0.f, 0.f}, c1 = {0.f, 0.f, 0.f, 0.f};
#pragma unroll
    for (int ks = 0; ks < 8; ++ks) {
      short8 bf = *(const short8*)(b0 + ks * 512);
      short8 x0 = *(const short8*)(A0 + (ks * 64 + lane) * 8);
      short8 x1 = *(const short8*)(A1 + (ks * 64 + lane) * 8);
      c0 = MFMA16(x0, bf, c0);
      c1 = MFMA16(x1, bf, c1);
    }
    int c = t * 16 + lm;
    float bias = cstg[896 + c];
#pragma unroll
    for (int G = 0; G < 2; ++G) {
      f32x4 acc = G ? c1 : c0;
      int rb = G * 16 + q * 4;
      if (c < 544) {
#pragma unroll
        for (int g = 0; g < 4; ++g) sm.u.w1a[rb + g][c] = f2us(fabsf(acc[g] + bias));
      } else {
        int e = c - 544;
#pragma unroll
        for (int g = 0; g < 4; ++g) sm.w2v[rb + g][e] = fabsf(acc[g] + bias);
      }
    }
  }
  __syncthreads();

  // ---- C1: w0c/w0s = relu(hb [+hd]) @ w00l2 + b ----
  if (tid < 256) {
    int r = tid >> 3, k = (tid >> 1) & 3, sflag = tid & 1;
    const float* wl = cstg + 1792;
    float a = 0.f;
    for (int j = 0; j < 256; ++j) {
      float h = us2f(sm.hb[r][j]);
      if (sflag) h += sm.hd[j];
      h = h > 0.f ? h : 0.f;
      a = fmaf(h, wl[j * 4 + k], a);
    }
    a += cstg[2816 + k];
    if (sflag) sm.w0s[r][k] = a; else sm.w0c[r][k] = a;
  }
  __syncthreads();

  // ---- C2: gq ----
  {
    int r = tid >> 4, v = tid & 15;
    bool sp = (v == b_blk);
    const float* w0 = sp ? sm.w0s[r] : sm.w0c[r];
    float g = sm.gbv[r] + (sp ? cstg[2853] : 0.f);
#pragma unroll
    for (int k = 0; k < 4; ++k) {
      int a = sm.cr[r][k * 16 + v];
      g = fmaf(sm.qv[r][a], fabsf(w0[k]), g);
    }
    sm.gq[r][v] = g;
  }
  if (tid < 32) {
    float o = sm.b01v[tid];
#pragma unroll
    for (int a = 0; a < 10; ++a) o = fmaf(sm.qv[tid][a], sm.w01v[tid][a], o);
    sm.gq[tid][16] = o;
  }
  __syncthreads();

  // ---- C3: hidden = elu(sum_v gq*|w1| + b1); fuse *w2 + rb*b2l2W ----
  for (int p = tid; p < 1024; p += 512) {
    int r = p >> 5, e = p & 31;
    float h = sm.b1v[r][e];
#pragma unroll
    for (int v = 0; v < 17; ++v) h = fmaf(sm.gq[r][v], us2f(sm.u.w1a[r][v * 32 + e]), h);
    float hid = h > 0.f ? h : (expf(h) - 1.f);
    sm.hid[r][e] = hid * sm.w2v[r][e] + sm.rbv[r][e] * cstg[2820 + e];
  }
  __syncthreads();

  // ---- C4: reduce + store ----
  if (tid < 32) {
    float y = cstg[2852];
#pragma unroll
    for (int e = 0; e < 32; ++e) y += sm.hid[tid][e];
    if (F32) ((float*)out)[n0 + tid] = y;
    else ((bf16*)out)[n0 + tid] = __float2bfloat16(y);
  }
}

__global__ __launch_bounds__(512, 2) void causal_mixer_mfma(const char* ws,
    const void* qvals, const int* crel, const void* states, void* out) {
  __shared__ SmemM sm;
  int n0 = blockIdx.x * 32;
  if (detect_f32(states))
    mixer_body<true>(sm, ws, n0, qvals, crel, states, out);
  else
    mixer_body<false>(sm, ws, n0, qvals, crel, states, out);
}

// ---------------- fallback scalar kernel (round-2, proven) ----------------
struct SmemF {
  float s[16][516]; float buf[16][258]; float hd[256];
  float q[16][10]; int cr[16][66];
  float w0c[16][4], w0s[16][4]; float gq[16][17];
  float w01[16][10]; float b01[16]; float gb[16]; float gd;
  float hid[16][32]; float w2[16][32]; float rb[16][32];
};

template <bool F32>
__device__ void fb_body(SmemF& sm, int tid, int n0, int b_blk,
    const void* qvals, const int* crel, const void* states,
    const void* w00l1W, const void* w00l1b, const void* w00l2W, const void* w00l2b,
    const void* b00W, const void* b00b,
    const void* w01W, const void* w01b, const void* b01W, const void* b01b,
    const void* w1l1W, const void* w1l1b, const void* w1l2W, const void* w1l2b,
    const void* b1W, const void* b1b,
    const void* w2l1W, const void* w2l1b, const void* w2l2W, const void* w2l2b,
    const void* b2l1W, const void* b2l1b, const void* b2l2W, const void* b2l2b,
    void* out) {
  for (int idx = tid; idx < 16 * 512; idx += 256) {
    int r = idx >> 9, i = idx & 511;
    sm.s[r][i] = LD<F32>(states, (size_t)(n0 + r) * 512 + i);
  }
  for (int idx = tid; idx < 160; idx += 256) {
    int r = idx / 10, a = idx % 10;
    sm.q[r][a] = LD<F32>(qvals, (size_t)(n0 + r) * 10 + a);
  }
  for (int idx = tid; idx < 16 * 64; idx += 256) {
    int r = idx >> 6, kv = idx & 63;
    sm.cr[r][kv] = crel[(size_t)(n0 + r) * 64 + kv];
  }
  if (tid == 0) {
    float gd = 0.f;
    for (int i = 512; i < 528; ++i) gd += LD<F32>(b00W, i);
    sm.gd = gd;
  }
  __syncthreads();
  {
    const int j = tid;
    float hd = 0.f;
    for (int i = 0; i < 16; ++i) hd += LD<F32>(w00l1W, (size_t)(512 + i) * 256 + j);
    sm.hd[j] = hd;
    float acc[16]; float bj = LD<F32>(w00l1b, j);
#pragma unroll
    for (int r = 0; r < 16; ++r) acc[r] = bj;
    for (int i = 0; i < 512; ++i) {
      float w = LD<F32>(w00l1W, (size_t)i * 256 + j);
#pragma unroll
      for (int r = 0; r < 16; ++r) acc[r] = fmaf(sm.s[r][i], w, acc[r]);
    }
#pragma unroll
    for (int r = 0; r < 16; ++r) sm.buf[r][j] = acc[r];
  }
  __syncthreads();
  if (tid < 64) {
    int r = tid >> 2, k = tid & 3;
    float aC = 0.f, aS = 0.f;
    for (int j = 0; j < 256; ++j) {
      float hb = sm.buf[r][j];
      float w = LD<F32>(w00l2W, j * 4 + k);
      float hc = hb > 0.f ? hb : 0.f;
      float hbs = hb + sm.hd[j];
      float hsv = hbs > 0.f ? hbs : 0.f;
      aC = fmaf(hc, w, aC); aS = fmaf(hsv, w, aS);
    }
    float bk = LD<F32>(w00l2b, k);
    sm.w0c[r][k] = aC + bk; sm.w0s[r][k] = aS + bk;
  } else if (tid < 224) {
    int p = tid - 64; int r = p / 10, a = p % 10;
    float acc = 0.f;
    for (int i = 0; i < 512; ++i) acc = fmaf(sm.s[r][i], LD<F32>(w01W, (size_t)i * 10 + a), acc);
    sm.w01[r][a] = acc + LD<F32>(w01b, a);
  } else if (tid < 240) {
    int r = tid - 224;
    float acc = 0.f;
    for (int i = 0; i < 512; ++i) acc = fmaf(sm.s[r][i], LD<F32>(b00W, i), acc);
    sm.gb[r] = acc + LD<F32>(b00b, 0);
  } else {
    int r = tid - 240;
    float acc = 0.f;
    for (int i = 0; i < 512; ++i) acc = fmaf(sm.s[r][i], LD<F32>(b01W, i), acc);
    sm.b01[r] = acc + LD<F32>(b01b, 0);
  }
  __syncthreads();
  {
    int r = tid >> 4, v = tid & 15;
    bool sp = (v == b_blk);
    const float* w0 = sp ? sm.w0s[r] : sm.w0c[r];
    float g = sm.gb[r] + (sp ? sm.gd : 0.f);
#pragma unroll
    for (int k = 0; k < 4; ++k) {
      int a = sm.cr[r][k * 16 + v];
      g = fmaf(sm.q[r][a], fabsf(w0[k]), g);
    }
    sm.gq[r][v] = g;
  }
  if (tid < 16) {
    int r = tid;
    float o = sm.b01[r];
    for (int a = 0; a < 10; ++a) o = fmaf(sm.q[r][a], sm.w01[r][a], o);
    sm.gq[r][16] = o;
  }
  __syncthreads();
  {
    const int j = tid;
    float acc[16]; float bj = LD<F32>(w1l1b, j);
#pragma unroll
    for (int r = 0; r < 16; ++r) acc[r] = bj;
    for (int i = 0; i < 512; ++i) {
      float w = LD<F32>(w1l1W, (size_t)i * 256 + j);
#pragma unroll
      for (int r = 0; r < 16; ++r) acc[r] = fmaf(sm.s[r][i], w, acc[r]);
    }
#pragma unroll
    for (int r = 0; r < 16; ++r) sm.buf[r][j] = acc[r] > 0.f ? acc[r] : 0.f;
  }
  __syncthreads();
  for (int p = tid; p < 512; p += 256) {
    int r = p >> 5, e = p & 31;
    float acc = 0.f;
    for (int v = 0; v < 17; ++v) {
      int c = v * 32 + e;
      float d = LD<F32>(w1l2b, c);
      for (int j = 0; j < 256; ++j) d = fmaf(sm.buf[r][j], LD<F32>(w1l2W, (size_t)j * 544 + c), d);
      acc = fmaf(sm.gq[r][v], fabsf(d), acc);
    }
    float b1v = LD<F32>(b1b, e);
    for (int i = 0; i < 512; ++i) b1v = fmaf(sm.s[r][i], LD<F32>(b1W, (size_t)i * 32 + e), b1v);
    float x = acc + b1v;
    sm.hid[r][e] = x > 0.f ? x : (expf(x) - 1.f);
  }
  __syncthreads();
  {
    const int j = tid;
    float acc[16]; float bj = LD<F32>(w2l1b, j);
#pragma unroll
    for (int r = 0; r < 16; ++r) acc[r] = bj;
    for (int i = 0; i < 512; ++i) {
      float w = LD<F32>(w2l1W, (size_t)i * 256 + j);
#pragma unroll
      for (int r = 0; r < 16; ++r) acc[r] = fmaf(sm.s[r][i], w, acc[r]);
    }
#pragma unroll
    for (int r = 0; r < 16; ++r) sm.buf[r][j] = acc[r] > 0.f ? acc[r] : 0.f;
  }
  __syncthreads();
  for (int p = tid; p < 512; p += 256) {
    int r = p >> 5, e = p & 31;
    float d = LD<F32>(w2l2b, e);
    for (int j = 0; j < 256; ++j) d = fmaf(sm.buf[r][j], LD<F32>(w2l2W, (size_t)j * 32 + e), d);
    sm.w2[r][e] = fabsf(d);
    float rb = LD<F32>(b2l1b, e);
    for (int i = 0; i < 512; ++i) rb = fmaf(sm.s[r][i], LD<F32>(b2l1W, (size_t)i * 32 + e), rb);
    sm.rb[r][e] = rb > 0.f ? rb : 0.f;
  }
  __syncthreads();
  if (tid < 16) {
    int r = tid;
    float y = 0.f;
#pragma unroll
    for (int e = 0; e < 32; ++e) y = fmaf(sm.hid[r][e], sm.w2[r][e], y);
    float b2v = LD<F32>(b2l2b, 0);
#pragma unroll
    for (int e = 0; e < 32; ++e) b2v = fmaf(sm.rb[r][e], LD<F32>(b2l2W, e), b2v);
    float yv = y + b2v;
    if (F32) ((float*)out)[n0 + r] = yv;
    else ((bf16*)out)[n0 + r] = __float2bfloat16(yv);
  }
}

__global__ __launch_bounds__(256) void causal_mixer_fb(
    const void* qvals, const int* crel, const void* states,
    const void* w00l1W, const void* w00l1b, const void* w00l2W, const void* w00l2b,
    const void* b00W, const void* b00b,
    const void* w01W, const void* w01b, const void* b01W, const void* b01b,
    const void* w1l1W, const void* w1l1b, const void* w1l2W, const void* w1l2b,
    const void* b1W, const void* b1b,
    const void* w2l1W, const void* w2l1b, const void* w2l2W, const void* w2l2b,
    const void* b2l1W, const void* b2l1b, const void* b2l2W, const void* b2l2b,
    void* out) {
  __shared__ SmemF sm;
  const int tid = threadIdx.x;
  const int n0 = blockIdx.x * 16;
  const int b_blk = n0 >> 6;
  if (detect_f32(states))
    fb_body<true>(sm, tid, n0, b_blk, qvals, crel, states, w00l1W, w00l1b, w00l2W, w00l2b,
        b00W, b00b, w01W, w01b, b01W, b01b, w1l1W, w1l1b, w1l2W, w1l2b, b1W, b1b,
        w2l1W, w2l1b, w2l2W, w2l2b, b2l1W, b2l1b, b2l2W, b2l2b, out);
  else
    fb_body<false>(sm, tid, n0, b_blk, qvals, crel, states, w00l1W, w00l1b, w00l2W, w00l2b,
        b00W, b00b, w01W, w01b, b01W, b01b, w1l1W, w1l1b, w1l2W, w1l2b, b1W, b1b,
        w2l1W, w2l1b, w2l2W, w2l2b, b2l1W, b2l1b, b2l2W, b2l2b, out);
}

extern "C" void kernel_launch(void* const* d_in, const int* in_sizes, int n_in,
                              void* d_out, int out_size, void* d_ws, size_t ws_size,
                              hipStream_t stream) {
  char* ws = (char*)d_ws;
  if (ws_size >= WS_NEED) {
    hipLaunchKernelGGL(prep_kernel, dim3(256), dim3(256), 0, stream, ws, d_in[2],
        d_in[3], d_in[4], d_in[5], d_in[6], d_in[7], d_in[8],
        d_in[9], d_in[10], d_in[11], d_in[12],
        d_in[13], d_in[14], d_in[15], d_in[16], d_in[17], d_in[18],
        d_in[19], d_in[20], d_in[21], d_in[22], d_in[23], d_in[24],
        d_in[25], d_in[26]);
    hipLaunchKernelGGL(causal_mixer_mfma, dim3(256), dim3(512), 0, stream, ws,
        d_in[0], (const int*)d_in[1], d_in[2], d_out);
  } else {
    hipLaunchKernelGGL(causal_mixer_fb, dim3(512), dim3(256), 0, stream,
        d_in[0], (const int*)d_in[1], d_in[2],
        d_in[3], d_in[4], d_in[5], d_in[6], d_in[7], d_in[8],
        d_in[9], d_in[10], d_in[11], d_in[12],
        d_in[13], d_in[14], d_in[15], d_in[16], d_in[17], d_in[18],
        d_in[19], d_in[20], d_in[21], d_in[22], d_in[23], d_in[24],
        d_in[25], d_in[26],
        d_out);
  }
}

// Round 8
// 167.777 us; speedup vs baseline: 1.5768x; 1.0514x over previous
//
#include <hip/hip_runtime.h>
#include <hip/hip_bf16.h>

// CausalMixer: B=128, T=64, NA=10, NV=16, K=4, SD=512, H=256, E=32. 8192 rows.
// Round 8: R7 structure + explicit software-pipelined B prefetch (nb/cb reg
// double-buffer, loads for strip s+8 issued before MFMAs of strip s) and
// source-major coalesced prep.

typedef __hip_bfloat16 bf16;
typedef unsigned short ushort_t;
typedef __attribute__((ext_vector_type(8))) short short8;
typedef __attribute__((ext_vector_type(4))) float f32x4;

#define PA_OFF 0
#define PA_TILES 56                                  // N=896 padded (844 real)
#define PB_OFF (PA_TILES * 16 * 64 * 8 * 2)          // 917504
#define PB_TILES 36                                  // N=576 exact
#define FB_OFF (PB_OFF + PB_TILES * 8 * 64 * 8 * 2)  // 1212416
#define NCST 2854
#define WS_NEED (size_t)(FB_OFF + NCST * 4 + 32)

#define MFMA16(a, b, c) __builtin_amdgcn_mfma_f32_16x16x32_bf16(a, b, c, 0, 0, 0)

__device__ __forceinline__ float us2f(ushort_t x) {
  unsigned u = ((unsigned)x) << 16; float f; __builtin_memcpy(&f, &u, 4); return f;
}
__device__ __forceinline__ ushort_t f2us(float v) {
  bf16 h = __float2bfloat16(v); ushort_t r; __builtin_memcpy(&r, &h, 2); return r;
}
template <bool F32>
__device__ __forceinline__ float LD(const void* p, size_t i) {
  if (F32) return ((const float*)p)[i];
  return us2f(((const ushort_t*)p)[i]);
}

// wave-level dtype probe: 1 = float32, 0 = bf16
__device__ __forceinline__ int detect_f32(const void* states) {
  const unsigned short* u = (const unsigned short*)states;
  int lane = threadIdx.x & 63;
  int bad = 0;
  for (int i = lane; i < 512; i += 64) {
    unsigned short x = u[i];
    int e = (x >> 7) & 0xFF;
    if (e > 140 || (((x & 0x7FFFu) != 0) && e < 100)) bad++;
  }
  for (int off = 32; off; off >>= 1) bad += __shfl_down(bad, off);
  return __shfl(bad, 0) > 20;
}

// packed-layout stores: element (n', k) -> MFMA lane order
__device__ __forceinline__ void pa_store(ushort_t* pa, int np, int k, ushort_t v) {
  int t = np >> 4, lm = np & 15, ks = k >> 5, qq = (k >> 3) & 3, j = k & 7;
  pa[(size_t)t * 8192 + ks * 512 + (qq * 16 + lm) * 8 + j] = v;
}
__device__ __forceinline__ void pb_store(ushort_t* pb, int np, int k, ushort_t v) {
  int t = np >> 4, lm = np & 15, ks = k >> 5, qq = (k >> 3) & 3, j = k & 7;
  pb[(size_t)t * 4096 + ks * 512 + (qq * 16 + lm) * 8 + j] = v;
}

// ---------------- prep: source-major coalesced reads, scattered u16 writes ----
template <bool F32>
__device__ void prep_body(int gtid, int T, char* ws,
    const void* w00l1W, const void* w00l1b, const void* w00l2W, const void* w00l2b,
    const void* b00W, const void* b00b,
    const void* w01W, const void* w01b, const void* b01W, const void* b01b,
    const void* w1l1W, const void* w1l1b, const void* w1l2W, const void* w1l2b,
    const void* b1W, const void* b1b,
    const void* w2l1W, const void* w2l1b, const void* w2l2W, const void* w2l2b,
    const void* b2l1W, const void* b2l1b, const void* b2l2W, const void* b2l2b) {
  ushort_t* pa = (ushort_t*)(ws + PA_OFF);
  ushort_t* pb = (ushort_t*)(ws + PB_OFF);
  float* cst = (float*)(ws + FB_OFF);
  // big (512,256) tensors: coalesced source reads
  for (int i = gtid; i < 131072; i += T) {
    int k = i >> 8, n = i & 255;
    pa_store(pa, n, k, f2us(LD<F32>(w1l1W, i)));
    pa_store(pa, 256 + n, k, f2us(LD<F32>(w2l1W, i)));
    pa_store(pa, 512 + n, k, f2us(LD<F32>(w00l1W, i)));   // rows 0..511 only
  }
  for (int i = gtid; i < 16384; i += T) {
    int k = i >> 5, n = i & 31;
    pa_store(pa, 768 + n, k, f2us(LD<F32>(b1W, i)));
    pa_store(pa, 800 + n, k, f2us(LD<F32>(b2l1W, i)));
  }
  for (int i = gtid; i < 5120; i += T) {
    int k = i / 10, n = i % 10;
    pa_store(pa, 832 + n, k, f2us(LD<F32>(w01W, i)));
  }
  for (int i = gtid; i < 512; i += T) {
    pa_store(pa, 842, i, f2us(LD<F32>(b00W, i)));
    pa_store(pa, 843, i, f2us(LD<F32>(b01W, i)));
  }
  // zero the garbage lanes of tile 52 (n' 844..847) so MFMA inputs are benign
  for (int z = gtid; z < 2048; z += T) {
    int ks = z >> 7, qq = (z >> 5) & 3, lm = 12 + ((z >> 3) & 3), j = z & 7;
    pa[(size_t)52 * 8192 + ks * 512 + (qq * 16 + lm) * 8 + j] = 0;
  }
  // PB
  for (int i = gtid; i < 139264; i += T) {
    int k = i / 544, n = i % 544;
    pb_store(pb, n, k, f2us(LD<F32>(w1l2W, i)));
  }
  for (int i = gtid; i < 8192; i += T) {
    int k = i >> 5, n = i & 31;
    pb_store(pb, 544 + n, k, f2us(LD<F32>(w2l2W, i)));
  }
  // consts: biasA[0,896) biasB[896,1536) hd[1536,1792) w00l2W[1792,2816)
  //         w00l2b[2816,2820) b2l2W[2820,2852) b2l2b[2852] gd[2853]
  for (int i = gtid; i < NCST; i += T) {
    float x;
    if (i < 896) {
      int c = i;
      if (c < 256) x = LD<F32>(w1l1b, c);
      else if (c < 512) x = LD<F32>(w2l1b, c - 256);
      else if (c < 768) x = LD<F32>(w00l1b, c - 512);
      else if (c < 800) x = LD<F32>(b1b, c - 768);
      else if (c < 832) x = LD<F32>(b2l1b, c - 800);
      else if (c < 842) x = LD<F32>(w01b, c - 832);
      else if (c == 842) x = LD<F32>(b00b, 0);
      else if (c == 843) x = LD<F32>(b01b, 0);
      else x = 0.f;
    } else if (i < 1536) {
      int c = i - 896;
      x = (c < 544) ? LD<F32>(w1l2b, c) : (c < 576 ? LD<F32>(w2l2b, c - 544) : 0.f);
    } else if (i < 1792) {
      int j = i - 1536; float s = 0.f;
      for (int z = 0; z < 16; ++z) s += LD<F32>(w00l1W, (size_t)(512 + z) * 256 + j);
      x = s;
    } else if (i < 2816) x = LD<F32>(w00l2W, i - 1792);
    else if (i < 2820) x = LD<F32>(w00l2b, i - 2816);
    else if (i < 2852) x = LD<F32>(b2l2W, i - 2820);
    else if (i == 2852) x = LD<F32>(b2l2b, 0);
    else { float s = 0.f; for (int z = 0; z < 16; ++z) s += LD<F32>(b00W, 512 + z); x = s; }
    cst[i] = x;
  }
}

__global__ __launch_bounds__(256) void prep_kernel(char* ws, const void* states,
    const void* w00l1W, const void* w00l1b, const void* w00l2W, const void* w00l2b,
    const void* b00W, const void* b00b,
    const void* w01W, const void* w01b, const void* b01W, const void* b01b,
    const void* w1l1W, const void* w1l1b, const void* w1l2W, const void* w1l2b,
    const void* b1W, const void* b1b,
    const void* w2l1W, const void* w2l1b, const void* w2l2W, const void* w2l2b,
    const void* b2l1W, const void* b2l1b, const void* b2l2W, const void* b2l2b) {
  int gtid = blockIdx.x * 256 + threadIdx.x;
  int T = gridDim.x * 256;
  if (detect_f32(states))
    prep_body<true>(gtid, T, ws, w00l1W, w00l1b, w00l2W, w00l2b, b00W, b00b,
        w01W, w01b, b01W, b01b, w1l1W, w1l1b, w1l2W, w1l2b, b1W, b1b,
        w2l1W, w2l1b, w2l2W, w2l2b, b2l1W, b2l1b, b2l2W, b2l2b);
  else
    prep_body<false>(gtid, T, ws, w00l1W, w00l1b, w00l2W, w00l2b, b00W, b00b,
        w01W, w01b, b01W, b01b, w1l1W, w1l1b, w1l2W, w1l2b, b1W, b1b,
        w2l1W, w2l1b, w2l2W, w2l2b, b2l1W, b2l1b, b2l2W, b2l2b);
}

// ---------------- main MFMA kernel: 32 rows/block, 8 waves ----------------
struct SmemM {
  union {
    __align__(16) ushort_t sA[2][8192];   // states, MFMA lane order (phase A only)
    __align__(16) ushort_t w1a[32][544];  // |w1 raw| bf16 (phase B output)
  } u;
  __align__(16) ushort_t Am1[2][4096];    // relu(s@w1l1+b), lane order
  __align__(16) ushort_t Am2[2][4096];    // relu(s@w2l1+b), lane order
  __align__(16) ushort_t hb[32][264];     // s@w00l1+b (pre-relu), linear
  float hd[256];
  float b1v[32][32];
  float rbv[32][32];
  float w2v[32][32];
  float w01v[32][12];
  float qv[32][10];
  unsigned char cr[32][64];
  float w0c[32][4], w0s[32][4];
  float gq[32][18];
  float gbv[32], b01v[32];
  float hid[32][33];
};

template <bool F32>
__device__ void mixer_body(SmemM& sm, const char* ws, int n0,
    const void* qvals, const int* crel, const void* states, void* out) {
  const int tid = threadIdx.x;                // 0..511
  const int lane = tid & 63, wv = tid >> 6;   // 8 waves
  const int q = lane >> 4, lm = lane & 15;
  const int b_blk = n0 >> 6;
  const ushort_t* pa = (const ushort_t*)(ws + PA_OFF);
  const ushort_t* pb = (const ushort_t*)(ws + PB_OFF);
  const float* cstg = (const float*)(ws + FB_OFF);

  // ---- stage: states -> sA in MFMA lane order; qv/cr; hd ----
  for (int fi = tid; fi < 2048; fi += 512) {
    int ln = fi & 63, ks = (fi >> 6) & 15, G = fi >> 10;
    int row = G * 16 + (ln & 15), col = ks * 32 + (ln >> 4) * 8;
    if (F32) {
      const f32x4* p = (const f32x4*)((const float*)states + (size_t)(n0 + row) * 512 + col);
      f32x4 v0 = p[0], v1 = p[1];
      ushort_t v[8];
      v[0] = f2us(v0[0]); v[1] = f2us(v0[1]); v[2] = f2us(v0[2]); v[3] = f2us(v0[3]);
      v[4] = f2us(v1[0]); v[5] = f2us(v1[1]); v[6] = f2us(v1[2]); v[7] = f2us(v1[3]);
      *(short8*)&sm.u.sA[G][(size_t)(ks * 64 + ln) * 8] = *(short8*)v;
    } else {
      *(short8*)&sm.u.sA[G][(size_t)(ks * 64 + ln) * 8] =
          *(const short8*)((const ushort_t*)states + (size_t)(n0 + row) * 512 + col);
    }
  }
  for (int i = tid; i < 320; i += 512) sm.qv[i / 10][i % 10] = LD<F32>(qvals, (size_t)(n0 + i / 10) * 10 + i % 10);
  for (int i = tid; i < 2048; i += 512) sm.cr[i >> 6][i & 63] = (unsigned char)crel[(size_t)n0 * 64 + i];
  if (tid < 256) sm.hd[tid] = cstg[1536 + tid];
  __syncthreads();

  // ---- Phase A: Y(32x844) = S @ WtA, 53 strips, K=512 ----
  // software-pipelined B: nb holds strip s+8's fragments, loaded before the
  // MFMAs of strip s execute.
  short8 nb[16];
  {
    const ushort_t* bp = pa + (size_t)wv * 8192 + lane * 8;
#pragma unroll
    for (int ks = 0; ks < 16; ++ks) nb[ks] = *(const short8*)(bp + ks * 512);
  }
  for (int s = wv; s < 53; s += 8) {
    short8 cb[16];
#pragma unroll
    for (int ks = 0; ks < 16; ++ks) cb[ks] = nb[ks];
    if (s + 8 < 53) {
      const ushort_t* bp = pa + (size_t)(s + 8) * 8192 + lane * 8;
#pragma unroll
      for (int ks = 0; ks < 16; ++ks) nb[ks] = *(const short8*)(bp + ks * 512);
    }
    f32x4 acc0 = {0.f, 0.f, 0.f, 0.f}, acc1 = {0.f, 0.f, 0.f, 0.f};
#pragma unroll
    for (int ks = 0; ks < 16; ++ks) {
      short8 a0 = *(const short8*)&sm.u.sA[0][(ks * 64 + lane) * 8];
      short8 a1 = *(const short8*)&sm.u.sA[1][(ks * 64 + lane) * 8];
      acc0 = MFMA16(a0, cb[ks], acc0);
      acc1 = MFMA16(a1, cb[ks], acc1);
    }
    int c = s * 16 + lm;
    if (c < 844) {
      float bias = cstg[c];
      int ks2 = (c & 255) >> 5, q2 = (c >> 3) & 3, j2 = c & 7;
#pragma unroll
      for (int G = 0; G < 2; ++G) {
        f32x4 acc = G ? acc1 : acc0;
        int rb = G * 16 + q * 4;
        if (c < 256) {
#pragma unroll
          for (int g = 0; g < 4; ++g) {
            float v = acc[g] + bias;
            sm.Am1[G][(ks2 * 64 + q2 * 16 + q * 4 + g) * 8 + j2] = f2us(v > 0.f ? v : 0.f);
          }
        } else if (c < 512) {
#pragma unroll
          for (int g = 0; g < 4; ++g) {
            float v = acc[g] + bias;
            sm.Am2[G][(ks2 * 64 + q2 * 16 + q * 4 + g) * 8 + j2] = f2us(v > 0.f ? v : 0.f);
          }
        } else if (c < 768) {
#pragma unroll
          for (int g = 0; g < 4; ++g) sm.hb[rb + g][c - 512] = f2us(acc[g] + bias);
        } else if (c < 800) {
#pragma unroll
          for (int g = 0; g < 4; ++g) sm.b1v[rb + g][c - 768] = acc[g] + bias;
        } else if (c < 832) {
#pragma unroll
          for (int g = 0; g < 4; ++g) { float v = acc[g] + bias; sm.rbv[rb + g][c - 800] = v > 0.f ? v : 0.f; }
        } else if (c < 842) {
#pragma unroll
          for (int g = 0; g < 4; ++g) sm.w01v[rb + g][c - 832] = acc[g] + bias;
        } else if (c == 842) {
#pragma unroll
          for (int g = 0; g < 4; ++g) sm.gbv[rb + g] = acc[g] + bias;
        } else {
#pragma unroll
          for (int g = 0; g < 4; ++g) sm.b01v[rb + g] = acc[g] + bias;
        }
      }
    }
  }
  __syncthreads();

  // ---- Phase B: strips 0..33 = m1 @ w1l2; 34..35 = m2 @ w2l2, K=256 ----
  // (w1a union overlays sA, dead after the barrier)
  short8 nb2[8];
  {
    const ushort_t* bp = pb + (size_t)wv * 4096 + lane * 8;
#pragma unroll
    for (int ks = 0; ks < 8; ++ks) nb2[ks] = *(const short8*)(bp + ks * 512);
  }
  for (int t = wv; t < 36; t += 8) {
    short8 cb2[8];
#pragma unroll
    for (int ks = 0; ks < 8; ++ks) cb2[ks] = nb2[ks];
    if (t + 8 < 36) {
      const ushort_t* bp = pb + (size_t)(t + 8) * 4096 + lane * 8;
#pragma unroll
      for (int ks = 0; ks < 8; ++ks) nb2[ks] = *(const short8*)(bp + ks * 512);
    }
    const ushort_t* A0 = (t < 34) ? sm.Am1[0] : sm.Am2[0];
    const ushort_t* A1 = (t < 34) ? sm.Am1[1] : sm.Am2[1];
    f32x4 c0 = {0.f, 0.f, 0.f, 0.f}, c1 = {0.f, 0.f, 0.f, 0.f};
#pragma unroll
    for (int ks = 0; ks < 8; ++ks) {
      short8 x0 = *(const short8*)(A0 + (ks * 64 + lane) * 8);
      short8 x1 = *(const short8*)(A1 + (ks * 64 + lane) * 8);
      c0 = MFMA16(x0, cb2[ks], c0);
      c1 = MFMA16(x1, cb2[ks], c1);
    }
    int c = t * 16 + lm;
    float bias = cstg[896 + c];
#pragma unroll
    for (int G = 0; G < 2; ++G) {
      f32x4 acc = G ? c1 : c0;
      int rb = G * 16 + q * 4;
      if (c < 544) {
#pragma unroll
        for (int g = 0; g < 4; ++g) sm.u.w1a[rb + g][c] = f2us(fabsf(acc[g] + bias));
      } else {
        int e = c - 544;
#pragma unroll
        for (int g = 0; g < 4; ++g) sm.w2v[rb + g][e] = fabsf(acc[g] + bias);
      }
    }
  }
  __syncthreads();

  // ---- C1: w0c/w0s = relu(hb [+hd]) @ w00l2 + b ----
  if (tid < 256) {
    int r = tid >> 3, k = (tid >> 1) & 3, sflag = tid & 1;
    const float* wl = cstg + 1792;
    float a = 0.f;
    for (int j = 0; j < 256; ++j) {
      float h = us2f(sm.hb[r][j]);
      if (sflag) h += sm.hd[j];
      h = h > 0.f ? h : 0.f;
      a = fmaf(h, wl[j * 4 + k], a);
    }
    a += cstg[2816 + k];
    if (sflag) sm.w0s[r][k] = a; else sm.w0c[r][k] = a;
  }
  __syncthreads();

  // ---- C2: gq ----
  {
    int r = tid >> 4, v = tid & 15;
    bool sp = (v == b_blk);
    const float* w0 = sp ? sm.w0s[r] : sm.w0c[r];
    float g = sm.gbv[r] + (sp ? cstg[2853] : 0.f);
#pragma unroll
    for (int k = 0; k < 4; ++k) {
      int a = sm.cr[r][k * 16 + v];
      g = fmaf(sm.qv[r][a], fabsf(w0[k]), g);
    }
    sm.gq[r][v] = g;
  }
  if (tid < 32) {
    float o = sm.b01v[tid];
#pragma unroll
    for (int a = 0; a < 10; ++a) o = fmaf(sm.qv[tid][a], sm.w01v[tid][a], o);
    sm.gq[tid][16] = o;
  }
  __syncthreads();

  // ---- C3: hidden = elu(sum_v gq*|w1| + b1); fuse *w2 + rb*b2l2W ----
  for (int p = tid; p < 1024; p += 512) {
    int r = p >> 5, e = p & 31;
    float h = sm.b1v[r][e];
#pragma unroll
    for (int v = 0; v < 17; ++v) h = fmaf(sm.gq[r][v], us2f(sm.u.w1a[r][v * 32 + e]), h);
    float hid = h > 0.f ? h : (expf(h) - 1.f);
    sm.hid[r][e] = hid * sm.w2v[r][e] + sm.rbv[r][e] * cstg[2820 + e];
  }
  __syncthreads();

  // ---- C4: reduce + store ----
  if (tid < 32) {
    float y = cstg[2852];
#pragma unroll
    for (int e = 0; e < 32; ++e) y += sm.hid[tid][e];
    if (F32) ((float*)out)[n0 + tid] = y;
    else ((bf16*)out)[n0 + tid] = __float2bfloat16(y);
  }
}

__global__ __launch_bounds__(512, 2) void causal_mixer_mfma(const char* ws,
    const void* qvals, const int* crel, const void* states, void* out) {
  __shared__ SmemM sm;
  int n0 = blockIdx.x * 32;
  if (detect_f32(states))
    mixer_body<true>(sm, ws, n0, qvals, crel, states, out);
  else
    mixer_body<false>(sm, ws, n0, qvals, crel, states, out);
}

// ---------------- fallback scalar kernel (round-2, proven) ----------------
struct SmemF {
  float s[16][516]; float buf[16][258]; float hd[256];
  float q[16][10]; int cr[16][66];
  float w0c[16][4], w0s[16][4]; float gq[16][17];
  float w01[16][10]; float b01[16]; float gb[16]; float gd;
  float hid[16][32]; float w2[16][32]; float rb[16][32];
};

template <bool F32>
__device__ void fb_body(SmemF& sm, int tid, int n0, int b_blk,
    const void* qvals, const int* crel, const void* states,
    const void* w00l1W, const void* w00l1b, const void* w00l2W, const void* w00l2b,
    const void* b00W, const void* b00b,
    const void* w01W, const void* w01b, const void* b01W, const void* b01b,
    const void* w1l1W, const void* w1l1b, const void* w1l2W, const void* w1l2b,
    const void* b1W, const void* b1b,
    const void* w2l1W, const void* w2l1b, const void* w2l2W, const void* w2l2b,
    const void* b2l1W, const void* b2l1b, const void* b2l2W, const void* b2l2b,
    void* out) {
  for (int idx = tid; idx < 16 * 512; idx += 256) {
    int r = idx >> 9, i = idx & 511;
    sm.s[r][i] = LD<F32>(states, (size_t)(n0 + r) * 512 + i);
  }
  for (int idx = tid; idx < 160; idx += 256) {
    int r = idx / 10, a = idx % 10;
    sm.q[r][a] = LD<F32>(qvals, (size_t)(n0 + r) * 10 + a);
  }
  for (int idx = tid; idx < 16 * 64; idx += 256) {
    int r = idx >> 6, kv = idx & 63;
    sm.cr[r][kv] = crel[(size_t)(n0 + r) * 64 + kv];
  }
  if (tid == 0) {
    float gd = 0.f;
    for (int i = 512; i < 528; ++i) gd += LD<F32>(b00W, i);
    sm.gd = gd;
  }
  __syncthreads();
  {
    const int j = tid;
    float hd = 0.f;
    for (int i = 0; i < 16; ++i) hd += LD<F32>(w00l1W, (size_t)(512 + i) * 256 + j);
    sm.hd[j] = hd;
    float acc[16]; float bj = LD<F32>(w00l1b, j);
#pragma unroll
    for (int r = 0; r < 16; ++r) acc[r] = bj;
    for (int i = 0; i < 512; ++i) {
      float w = LD<F32>(w00l1W, (size_t)i * 256 + j);
#pragma unroll
      for (int r = 0; r < 16; ++r) acc[r] = fmaf(sm.s[r][i], w, acc[r]);
    }
#pragma unroll
    for (int r = 0; r < 16; ++r) sm.buf[r][j] = acc[r];
  }
  __syncthreads();
  if (tid < 64) {
    int r = tid >> 2, k = tid & 3;
    float aC = 0.f, aS = 0.f;
    for (int j = 0; j < 256; ++j) {
      float hb = sm.buf[r][j];
      float w = LD<F32>(w00l2W, j * 4 + k);
      float hc = hb > 0.f ? hb : 0.f;
      float hbs = hb + sm.hd[j];
      float hsv = hbs > 0.f ? hbs : 0.f;
      aC = fmaf(hc, w, aC); aS = fmaf(hsv, w, aS);
    }
    float bk = LD<F32>(w00l2b, k);
    sm.w0c[r][k] = aC + bk; sm.w0s[r][k] = aS + bk;
  } else if (tid < 224) {
    int p = tid - 64; int r = p / 10, a = p % 10;
    float acc = 0.f;
    for (int i = 0; i < 512; ++i) acc = fmaf(sm.s[r][i], LD<F32>(w01W, (size_t)i * 10 + a), acc);
    sm.w01[r][a] = acc + LD<F32>(w01b, a);
  } else if (tid < 240) {
    int r = tid - 224;
    float acc = 0.f;
    for (int i = 0; i < 512; ++i) acc = fmaf(sm.s[r][i], LD<F32>(b00W, i), acc);
    sm.gb[r] = acc + LD<F32>(b00b, 0);
  } else {
    int r = tid - 240;
    float acc = 0.f;
    for (int i = 0; i < 512; ++i) acc = fmaf(sm.s[r][i], LD<F32>(b01W, i), acc);
    sm.b01[r] = acc + LD<F32>(b01b, 0);
  }
  __syncthreads();
  {
    int r = tid >> 4, v = tid & 15;
    bool sp = (v == b_blk);
    const float* w0 = sp ? sm.w0s[r] : sm.w0c[r];
    float g = sm.gb[r] + (sp ? sm.gd : 0.f);
#pragma unroll
    for (int k = 0; k < 4; ++k) {
      int a = sm.cr[r][k * 16 + v];
      g = fmaf(sm.q[r][a], fabsf(w0[k]), g);
    }
    sm.gq[r][v] = g;
  }
  if (tid < 16) {
    int r = tid;
    float o = sm.b01[r];
    for (int a = 0; a < 10; ++a) o = fmaf(sm.q[r][a], sm.w01[r][a], o);
    sm.gq[r][16] = o;
  }
  __syncthreads();
  {
    const int j = tid;
    float acc[16]; float bj = LD<F32>(w1l1b, j);
#pragma unroll
    for (int r = 0; r < 16; ++r) acc[r] = bj;
    for (int i = 0; i < 512; ++i) {
      float w = LD<F32>(w1l1W, (size_t)i * 256 + j);
#pragma unroll
      for (int r = 0; r < 16; ++r) acc[r] = fmaf(sm.s[r][i], w, acc[r]);
    }
#pragma unroll
    for (int r = 0; r < 16; ++r) sm.buf[r][j] = acc[r] > 0.f ? acc[r] : 0.f;
  }
  __syncthreads();
  for (int p = tid; p < 512; p += 256) {
    int r = p >> 5, e = p & 31;
    float acc = 0.f;
    for (int v = 0; v < 17; ++v) {
      int c = v * 32 + e;
      float d = LD<F32>(w1l2b, c);
      for (int j = 0; j < 256; ++j) d = fmaf(sm.buf[r][j], LD<F32>(w1l2W, (size_t)j * 544 + c), d);
      acc = fmaf(sm.gq[r][v], fabsf(d), acc);
    }
    float b1v = LD<F32>(b1b, e);
    for (int i = 0; i < 512; ++i) b1v = fmaf(sm.s[r][i], LD<F32>(b1W, (size_t)i * 32 + e), b1v);
    float x = acc + b1v;
    sm.hid[r][e] = x > 0.f ? x : (expf(x) - 1.f);
  }
  __syncthreads();
  {
    const int j = tid;
    float acc[16]; float bj = LD<F32>(w2l1b, j);
#pragma unroll
    for (int r = 0; r < 16; ++r) acc[r] = bj;
    for (int i = 0; i < 512; ++i) {
      float w = LD<F32>(w2l1W, (size_t)i * 256 + j);
#pragma unroll
      for (int r = 0; r < 16; ++r) acc[r] = fmaf(sm.s[r][i], w, acc[r]);
    }
#pragma unroll
    for (int r = 0; r < 16; ++r) sm.buf[r][j] = acc[r] > 0.f ? acc[r] : 0.f;
  }
  __syncthreads();
  for (int p = tid; p < 512; p += 256) {
    int r = p >> 5, e = p & 31;
    float d = LD<F32>(w2l2b, e);
    for (int j = 0; j < 256; ++j) d = fmaf(sm.buf[r][j], LD<F32>(w2l2W, (size_t)j * 32 + e), d);
    sm.w2[r][e] = fabsf(d);
    float rb = LD<F32>(b2l1b, e);
    for (int i = 0; i < 512; ++i) rb = fmaf(sm.s[r][i], LD<F32>(b2l1W, (size_t)i * 32 + e), rb);
    sm.rb[r][e] = rb > 0.f ? rb : 0.f;
  }
  __syncthreads();
  if (tid < 16) {
    int r = tid;
    float y = 0.f;
#pragma unroll
    for (int e = 0; e < 32; ++e) y = fmaf(sm.hid[r][e], sm.w2[r][e], y);
    float b2v = LD<F32>(b2l2b, 0);
#pragma unroll
    for (int e = 0; e < 32; ++e) b2v = fmaf(sm.rb[r][e], LD<F32>(b2l2W, e), b2v);
    float yv = y + b2v;
    if (F32) ((float*)out)[n0 + r] = yv;
    else ((bf16*)out)[n0 + r] = __float2bfloat16(yv);
  }
}

__global__ __launch_bounds__(256) void causal_mixer_fb(
    const void* qvals, const int* crel, const void* states,
    const void* w00l1W, const void* w00l1b, const void* w00l2W, const void* w00l2b,
    const void* b00W, const void* b00b,
    const void* w01W, const void* w01b, const void* b01W, const void* b01b,
    const void* w1l1W, const void* w1l1b, const void* w1l2W, const void* w1l2b,
    const void* b1W, const void* b1b,
    const void* w2l1W, const void* w2l1b, const void* w2l2W, const void* w2l2b,
    const void* b2l1W, const void* b2l1b, const void* b2l2W, const void* b2l2b,
    void* out) {
  __shared__ SmemF sm;
  const int tid = threadIdx.x;
  const int n0 = blockIdx.x * 16;
  const int b_blk = n0 >> 6;
  if (detect_f32(states))
    fb_body<true>(sm, tid, n0, b_blk, qvals, crel, states, w00l1W, w00l1b, w00l2W, w00l2b,
        b00W, b00b, w01W, w01b, b01W, b01b, w1l1W, w1l1b, w1l2W, w1l2b, b1W, b1b,
        w2l1W, w2l1b, w2l2W, w2l2b, b2l1W, b2l1b, b2l2W, b2l2b, out);
  else
    fb_body<false>(sm, tid, n0, b_blk, qvals, crel, states, w00l1W, w00l1b, w00l2W, w00l2b,
        b00W, b00b, w01W, w01b, b01W, b01b, w1l1W, w1l1b, w1l2W, w1l2b, b1W, b1b,
        w2l1W, w2l1b, w2l2W, w2l2b, b2l1W, b2l1b, b2l2W, b2l2b, out);
}

extern "C" void kernel_launch(void* const* d_in, const int* in_sizes, int n_in,
                              void* d_out, int out_size, void* d_ws, size_t ws_size,
                              hipStream_t stream) {
  char* ws = (char*)d_ws;
  if (ws_size >= WS_NEED) {
    hipLaunchKernelGGL(prep_kernel, dim3(256), dim3(256), 0, stream, ws, d_in[2],
        d_in[3], d_in[4], d_in[5], d_in[6], d_in[7], d_in[8],
        d_in[9], d_in[10], d_in[11], d_in[12],
        d_in[13], d_in[14], d_in[15], d_in[16], d_in[17], d_in[18],
        d_in[19], d_in[20], d_in[21], d_in[22], d_in[23], d_in[24],
        d_in[25], d_in[26]);
    hipLaunchKernelGGL(causal_mixer_mfma, dim3(256), dim3(512), 0, stream, ws,
        d_in[0], (const int*)d_in[1], d_in[2], d_out);
  } else {
    hipLaunchKernelGGL(causal_mixer_fb, dim3(512), dim3(256), 0, stream,
        d_in[0], (const int*)d_in[1], d_in[2],
        d_in[3], d_in[4], d_in[5], d_in[6], d_in[7], d_in[8],
        d_in[9], d_in[10], d_in[11], d_in[12],
        d_in[13], d_in[14], d_in[15], d_in[16], d_in[17], d_in[18],
        d_in[19], d_in[20], d_in[21], d_in[22], d_in[23], d_in[24],
        d_in[25], d_in[26],
        d_out);
  }
}